// Round 1
// baseline (1457.066 us; speedup 1.0000x reference)
//
#include <hip/hip_runtime.h>
#include <math.h>

// ---------------- CSR build ----------------

__global__ void init_k(int* cnt, int* deg, int* cursor, int n) {
    int i = blockIdx.x * 256 + threadIdx.x;
    if (i < n) { cnt[i] = 0; deg[i] = 1; }   // deg starts at 1 (self loop)
    if (i == 0) cursor[0] = 0;
}

__global__ void count_k(const int* __restrict__ src, const int* __restrict__ dst,
                        int* cnt, int* deg, int E) {
    int e = blockIdx.x * 256 + threadIdx.x;
    if (e < E) {
        atomicAdd(&cnt[dst[e]], 1);
        atomicAdd(&deg[src[e]], 1);
    }
}

__global__ void alloc_k(const int* __restrict__ cnt, const int* __restrict__ deg,
                        int* off, int* fil, float* invdeg, int* cursor, int n) {
    int i = blockIdx.x * 256 + threadIdx.x;
    if (i < n) {
        off[i] = atomicAdd(cursor, cnt[i]);
        fil[i] = 0;
        invdeg[i] = 1.0f / (float)deg[i];
    }
}

__global__ void fill_k(const int* __restrict__ src, const int* __restrict__ dst,
                       const int* __restrict__ off, int* fil, int* csr, int E) {
    int e = blockIdx.x * 256 + threadIdx.x;
    if (e < E) {
        int d = dst[e];
        int p = atomicAdd(&fil[d], 1);
        csr[off[d] + p] = src[e];
    }
}

// ---------------- attention softmax (tiny) ----------------

__global__ void att_k(const float* __restrict__ att, float* att_sm) {
    int b = threadIdx.x;
    if (b < 32) {
        float v0 = att[b], v1 = att[32 + b], v2 = att[64 + b], v3 = att[96 + b];
        float m = fmaxf(fmaxf(v0, v1), fmaxf(v2, v3));
        float e0 = expf(v0 - m), e1 = expf(v1 - m), e2 = expf(v2 - m), e3 = expf(v3 - m);
        float inv = 1.0f / (e0 + e1 + e2 + e3);
        att_sm[b] = e0 * inv; att_sm[32 + b] = e1 * inv;
        att_sm[64 + b] = e2 * inv; att_sm[96 + b] = e3 * inv;
    }
}

// ---------------- fused encoder MLP + rotation + linear ----------------
// LDS: w1 32KB + w2 8KB + lin_w 64KB + x-tile 33KB + hmid/cs 16KB = 153KB

__global__ __launch_bounds__(256, 1) void transform_k(
    const float* __restrict__ x,
    const float* __restrict__ lin_w, const float* __restrict__ lin_b,
    const float* __restrict__ w1, const float* __restrict__ b1,
    const float* __restrict__ w2, const float* __restrict__ b2,
    float* __restrict__ h0, float* __restrict__ cs_out,
    int n_nodes, int n_tiles)
{
    __shared__ float s_w1[128 * 64];
    __shared__ float s_w2[64 * 32];
    __shared__ float s_lw[128 * 128];
    __shared__ float s_x[64 * 132];   // padded stride 132
    __shared__ float s_h[64 * 64];    // hmid, then reused for cos/sin
    const int t = threadIdx.x;

    for (int i = t; i < 128 * 64 / 4; i += 256) ((float4*)s_w1)[i] = ((const float4*)w1)[i];
    for (int i = t; i < 64 * 32 / 4; i += 256)  ((float4*)s_w2)[i] = ((const float4*)w2)[i];
    for (int i = t; i < 128 * 128 / 4; i += 256) ((float4*)s_lw)[i] = ((const float4*)lin_w)[i];

    for (int tile = blockIdx.x; tile < n_tiles; tile += gridDim.x) {
        const int base = tile * 64;
        __syncthreads();   // protect s_x/s_h reuse from previous tile
        // stage 64x128 x tile
        for (int i = t; i < 64 * 32; i += 256) {
            int r = i >> 5, q = i & 31;
            int n = base + r;
            float4 v = make_float4(0.f, 0.f, 0.f, 0.f);
            if (n < n_nodes) v = ((const float4*)x)[(size_t)n * 32 + q];
            ((float4*)&s_x[r * 132])[q] = v;
        }
        __syncthreads();
        // phase A: hmid = gelu(x @ w1 + b1)    [64 x 64]
        {
            const int tx = t & 15, ty = t >> 4;
            float4 bv = ((const float4*)b1)[tx];
            float acc[4][4];
            #pragma unroll
            for (int i = 0; i < 4; i++) { acc[i][0] = bv.x; acc[i][1] = bv.y; acc[i][2] = bv.z; acc[i][3] = bv.w; }
            for (int k = 0; k < 128; k++) {
                float4 w = ((float4*)s_w1)[k * 16 + tx];
                #pragma unroll
                for (int i = 0; i < 4; i++) {
                    float xv = s_x[(ty * 4 + i) * 132 + k];
                    acc[i][0] += xv * w.x; acc[i][1] += xv * w.y;
                    acc[i][2] += xv * w.z; acc[i][3] += xv * w.w;
                }
            }
            #pragma unroll
            for (int i = 0; i < 4; i++)
                #pragma unroll
                for (int j = 0; j < 4; j++) {
                    float v = acc[i][j];
                    s_h[(ty * 4 + i) * 64 + tx * 4 + j] = 0.5f * v * (1.0f + erff(v * 0.70710678118654752f));
                }
        }
        __syncthreads();
        // phase B: theta = pi*tanh(hmid @ w2 + b2) -> c,s   [64 x 32]
        float cr[2][4], sr[2][4];
        {
            const int tx = t & 7, ty = t >> 3;
            float4 bv = ((const float4*)b2)[tx];
            float acc[2][4];
            #pragma unroll
            for (int i = 0; i < 2; i++) { acc[i][0] = bv.x; acc[i][1] = bv.y; acc[i][2] = bv.z; acc[i][3] = bv.w; }
            for (int k = 0; k < 64; k++) {
                float4 w = ((float4*)s_w2)[k * 8 + tx];
                #pragma unroll
                for (int i = 0; i < 2; i++) {
                    float hv = s_h[(ty * 2 + i) * 64 + k];
                    acc[i][0] += hv * w.x; acc[i][1] += hv * w.y;
                    acc[i][2] += hv * w.z; acc[i][3] += hv * w.w;
                }
            }
            #pragma unroll
            for (int i = 0; i < 2; i++)
                #pragma unroll
                for (int j = 0; j < 4; j++) {
                    float th = 3.14159265358979323846f * tanhf(acc[i][j]);
                    sincosf(th, &sr[i][j], &cr[i][j]);
                }
        }
        __syncthreads();   // all hmid reads done; reuse s_h for c,s
        {
            const int tx = t & 7, ty = t >> 3;
            #pragma unroll
            for (int i = 0; i < 2; i++) {
                int r = ty * 2 + i;
                int n = base + r;
                float4 cv = make_float4(cr[i][0], cr[i][1], cr[i][2], cr[i][3]);
                float4 sv = make_float4(sr[i][0], sr[i][1], sr[i][2], sr[i][3]);
                ((float4*)&s_h[r * 64])[tx] = cv;
                ((float4*)&s_h[r * 64 + 32])[tx] = sv;
                if (n < n_nodes) {
                    ((float4*)&cs_out[(size_t)n * 64])[tx] = cv;
                    ((float4*)&cs_out[(size_t)n * 64 + 32])[tx] = sv;
                }
            }
        }
        __syncthreads();
        // phase C: rotate x tile in place (vf layout: [b][i][dd], d=2)
        for (int i = t; i < 64 * 32; i += 256) {
            int r = i >> 5, b = i & 31;
            float c = s_h[r * 64 + b], s = s_h[r * 64 + 32 + b];
            float* xr = &s_x[r * 132 + b * 4];
            float v00 = xr[0], v01 = xr[1], v10 = xr[2], v11 = xr[3];
            xr[0] = c * v00 - s * v10;
            xr[1] = c * v01 - s * v11;
            xr[2] = s * v00 + c * v10;
            xr[3] = s * v01 + c * v11;
        }
        __syncthreads();
        // phase D: h0 = rx @ lin_w + lin_b     [64 x 128]
        {
            const int tx = t & 31, ty = t >> 5;
            float4 bv = ((const float4*)lin_b)[tx];
            float acc[8][4];
            #pragma unroll
            for (int i = 0; i < 8; i++) { acc[i][0] = bv.x; acc[i][1] = bv.y; acc[i][2] = bv.z; acc[i][3] = bv.w; }
            for (int k = 0; k < 128; k++) {
                float4 w = ((float4*)s_lw)[k * 32 + tx];
                #pragma unroll
                for (int i = 0; i < 8; i++) {
                    float xv = s_x[(ty * 8 + i) * 132 + k];
                    acc[i][0] += xv * w.x; acc[i][1] += xv * w.y;
                    acc[i][2] += xv * w.z; acc[i][3] += xv * w.w;
                }
            }
            #pragma unroll
            for (int i = 0; i < 8; i++) {
                int n = base + ty * 8 + i;
                if (n < n_nodes)
                    ((float4*)&h0[(size_t)n * 128])[tx] =
                        make_float4(acc[i][0], acc[i][1], acc[i][2], acc[i][3]);
            }
        }
    }
}

// ---------------- propagation: one wave per node ----------------

__global__ __launch_bounds__(256) void prop_k(
    const float* __restrict__ hin, float* __restrict__ hout,
    const int* __restrict__ csr, const int* __restrict__ off,
    const int* __restrict__ cnt, const float* __restrict__ invdeg,
    const float* __restrict__ att_sm, int att_row, float* __restrict__ acc,
    int init_acc, int n_nodes)
{
    int gw = (int)((blockIdx.x * 256 + threadIdx.x) >> 6);
    int lane = threadIdx.x & 63;
    if (gw >= n_nodes) return;
    int o = off[gw], c = cnt[gw];
    const float2* h2 = (const float2*)hin;
    size_t selfidx = (size_t)gw * 64 + lane;
    float2 a = h2[selfidx];           // self loop
    int j = 0;
    for (; j + 4 <= c; j += 4) {
        int s0 = csr[o + j], s1 = csr[o + j + 1], s2 = csr[o + j + 2], s3 = csr[o + j + 3];
        float2 v0 = h2[(size_t)s0 * 64 + lane];
        float2 v1 = h2[(size_t)s1 * 64 + lane];
        float2 v2 = h2[(size_t)s2 * 64 + lane];
        float2 v3 = h2[(size_t)s3 * 64 + lane];
        a.x += (v0.x + v1.x) + (v2.x + v3.x);
        a.y += (v0.y + v1.y) + (v2.y + v3.y);
    }
    for (; j < c; ++j) {
        int s = csr[o + j];
        float2 v = h2[(size_t)s * 64 + lane];
        a.x += v.x; a.y += v.y;
    }
    float id = invdeg[gw];
    a.x *= id; a.y *= id;
    ((float2*)hout)[selfidx] = a;
    if (att_row >= 0) {
        float wv = att_sm[att_row * 32 + (lane >> 1)];
        float2* a2 = (float2*)acc;
        float2 res = make_float2(wv * a.x, wv * a.y);
        if (!init_acc) { float2 p = a2[selfidx]; res.x += p.x; res.y += p.y; }
        a2[selfidx] = res;
    }
}

// ---------------- inverse rotation + residual ----------------

__global__ __launch_bounds__(256) void final_k(
    const float* __restrict__ x, const float* __restrict__ cs,
    float* __restrict__ out, int n_nodes)
{
    int i = blockIdx.x * 256 + threadIdx.x;   // (n, b)
    if (i >= n_nodes * 32) return;
    int n = i >> 5, b = i & 31;
    float c = cs[(size_t)n * 64 + b], s = cs[(size_t)n * 64 + 32 + b];
    float4 v = ((float4*)out)[i];             // acc lives in d_out
    float4 xv = ((const float4*)x)[i];
    float o0 =  c * v.x + s * v.z;
    float o1 =  c * v.y + s * v.w;
    float o2 = -s * v.x + c * v.z;
    float o3 = -s * v.y + c * v.w;
    ((float4*)out)[i] = make_float4(xv.x + o0, xv.y + o1, xv.z + o2, xv.w + o3);
}

// ---------------- launch ----------------

extern "C" void kernel_launch(void* const* d_in, const int* in_sizes, int n_in,
                              void* d_out, int out_size, void* d_ws, size_t ws_size,
                              hipStream_t stream) {
    const float* x     = (const float*)d_in[0];
    const int*   ei    = (const int*)d_in[1];
    const float* lin_w = (const float*)d_in[2];
    const float* lin_b = (const float*)d_in[3];
    const float* w1    = (const float*)d_in[4];
    const float* b1    = (const float*)d_in[5];
    const float* w2    = (const float*)d_in[6];
    const float* b2    = (const float*)d_in[7];
    const float* att   = (const float*)d_in[8];
    const int N = in_sizes[0] / 128;
    const int E = in_sizes[1] / 2;
    const int* srcp = ei;
    const int* dstp = ei + E;
    float* out = (float*)d_out;

    char* w = (char*)d_ws;
    auto walloc = [&](size_t bytes) { char* p = w; w += (bytes + 255) & ~255UL; return p; };
    int*   cnt    = (int*)walloc((size_t)N * 4);
    int*   deg    = (int*)walloc((size_t)N * 4);
    int*   off    = (int*)walloc((size_t)N * 4);
    int*   fil    = (int*)walloc((size_t)N * 4);
    float* invdeg = (float*)walloc((size_t)N * 4);
    int*   cursor = (int*)walloc(256);
    float* att_sm = (float*)walloc(512);
    int*   csr    = (int*)walloc((size_t)E * 4);
    float* cs     = (float*)walloc((size_t)N * 64 * 4);
    float* bufA   = (float*)walloc((size_t)N * 128 * 4);
    float* bufB   = (float*)walloc((size_t)N * 128 * 4);

    int nb_n = (N + 255) / 256;
    int nb_e = (E + 255) / 256;
    hipLaunchKernelGGL(init_k,  dim3(nb_n), dim3(256), 0, stream, cnt, deg, cursor, N);
    hipLaunchKernelGGL(count_k, dim3(nb_e), dim3(256), 0, stream, srcp, dstp, cnt, deg, E);
    hipLaunchKernelGGL(alloc_k, dim3(nb_n), dim3(256), 0, stream, cnt, deg, off, fil, invdeg, cursor, N);
    hipLaunchKernelGGL(fill_k,  dim3(nb_e), dim3(256), 0, stream, srcp, dstp, off, fil, csr, E);
    hipLaunchKernelGGL(att_k,   dim3(1),    dim3(64),  0, stream, att, att_sm);

    int n_tiles = (N + 63) / 64;
    hipLaunchKernelGGL(transform_k, dim3(512), dim3(256), 0, stream,
                       x, lin_w, lin_b, w1, b1, w2, b2, bufA, cs, N, n_tiles);

    // 8 propagation steps; checkpoints (att rows) after steps 1,2,4,8
    int ckpt[9] = {-1, 0, 1, -1, 2, -1, -1, -1, 3};
    float* hi = bufA; float* ho = bufB;
    int pb = (N * 64 + 255) / 256;
    for (int step = 1; step <= 8; ++step) {
        hipLaunchKernelGGL(prop_k, dim3(pb), dim3(256), 0, stream,
                           hi, ho, csr, off, cnt, invdeg, att_sm, ckpt[step], out,
                           (step == 1) ? 1 : 0, N);
        float* tmp = hi; hi = ho; ho = tmp;
    }

    int fb = (N * 32 + 255) / 256;
    hipLaunchKernelGGL(final_k, dim3(fb), dim3(256), 0, stream, x, cs, out, N);
}

// Round 2
// 1122.882 us; speedup vs baseline: 1.2976x; 1.2976x over previous
//
#include <hip/hip_runtime.h>
#include <math.h>

typedef unsigned int uint;

// ---------------- bf16 helpers ----------------

__device__ __forceinline__ float bf_lo(uint u) { return __uint_as_float(u << 16); }
__device__ __forceinline__ float bf_hi(uint u) { return __uint_as_float(u & 0xFFFF0000u); }
__device__ __forceinline__ uint pack_bf16(float x, float y) {
    uint ux = __float_as_uint(x), uy = __float_as_uint(y);
    ux += 0x7FFFu + ((ux >> 16) & 1u);          // RTNE
    uy += 0x7FFFu + ((uy >> 16) & 1u);
    return (ux >> 16) | (uy & 0xFFFF0000u);
}

// ---------------- CSR build ----------------

__global__ void init_k(int* cnt, int* deg, int* cursor, int n) {
    int i = blockIdx.x * 256 + threadIdx.x;
    if (i < n) { cnt[i] = 0; deg[i] = 1; }   // deg starts at 1 (self loop)
    if (i == 0) cursor[0] = 0;
}

__global__ void count_k(const int* __restrict__ src, const int* __restrict__ dst,
                        int* cnt, int* deg, int E) {
    int e = blockIdx.x * 256 + threadIdx.x;
    if (e < E) {
        atomicAdd(&cnt[dst[e]], 1);
        atomicAdd(&deg[src[e]], 1);
    }
}

__global__ void alloc_k(const int* __restrict__ cnt, const int* __restrict__ deg,
                        int* off, int* fil, float* invdeg, int* cursor, int n) {
    int i = blockIdx.x * 256 + threadIdx.x;
    if (i < n) {
        off[i] = atomicAdd(cursor, cnt[i]);
        fil[i] = 0;
        invdeg[i] = 1.0f / (float)deg[i];
    }
}

__global__ void fill_k(const int* __restrict__ src, const int* __restrict__ dst,
                       const int* __restrict__ off, int* fil, int* csr, int E) {
    int e = blockIdx.x * 256 + threadIdx.x;
    if (e < E) {
        int d = dst[e];
        int p = atomicAdd(&fil[d], 1);
        csr[off[d] + p] = src[e];
    }
}

// ---------------- attention softmax (tiny) ----------------

__global__ void att_k(const float* __restrict__ att, float* att_sm) {
    int b = threadIdx.x;
    if (b < 32) {
        float v0 = att[b], v1 = att[32 + b], v2 = att[64 + b], v3 = att[96 + b];
        float m = fmaxf(fmaxf(v0, v1), fmaxf(v2, v3));
        float e0 = expf(v0 - m), e1 = expf(v1 - m), e2 = expf(v2 - m), e3 = expf(v3 - m);
        float inv = 1.0f / (e0 + e1 + e2 + e3);
        att_sm[b] = e0 * inv; att_sm[32 + b] = e1 * inv;
        att_sm[64 + b] = e2 * inv; att_sm[96 + b] = e3 * inv;
    }
}

// ---------------- fused encoder MLP + rotation + linear ----------------
// LDS: w2 8KB + x-tile 33KB + hmid/cs 16KB = 57KB -> 2 blocks/CU.
// w1 (32KB, L1-resident) and lin_w (64KB, L2-resident) streamed from global.

__global__ __launch_bounds__(256) void transform_k(
    const float* __restrict__ x,
    const float* __restrict__ lin_w, const float* __restrict__ lin_b,
    const float* __restrict__ w1, const float* __restrict__ b1,
    const float* __restrict__ w2, const float* __restrict__ b2,
    uint* __restrict__ h0, float* __restrict__ cs_out,
    int n_nodes, int n_tiles)
{
    __shared__ float s_w2[64 * 32];
    __shared__ float s_x[64 * 132];   // padded stride 132
    __shared__ float s_h[64 * 64];    // hmid, then reused for cos/sin
    const int t = threadIdx.x;

    for (int i = t; i < 64 * 32 / 4; i += 256)  ((float4*)s_w2)[i] = ((const float4*)w2)[i];

    for (int tile = blockIdx.x; tile < n_tiles; tile += gridDim.x) {
        const int base = tile * 64;
        __syncthreads();   // protect s_x/s_h reuse from previous tile
        // stage 64x128 x tile
        for (int i = t; i < 64 * 32; i += 256) {
            int r = i >> 5, q = i & 31;
            int n = base + r;
            float4 v = make_float4(0.f, 0.f, 0.f, 0.f);
            if (n < n_nodes) v = ((const float4*)x)[(size_t)n * 32 + q];
            ((float4*)&s_x[r * 132])[q] = v;
        }
        __syncthreads();
        // phase A: hmid = gelu(x @ w1 + b1)    [64 x 64]
        {
            const int tx = t & 15, ty = t >> 4;
            float4 bv = ((const float4*)b1)[tx];
            float acc[4][4];
            #pragma unroll
            for (int i = 0; i < 4; i++) { acc[i][0] = bv.x; acc[i][1] = bv.y; acc[i][2] = bv.z; acc[i][3] = bv.w; }
            #pragma unroll 4
            for (int k = 0; k < 128; k++) {
                float4 w = ((const float4*)w1)[k * 16 + tx];
                #pragma unroll
                for (int i = 0; i < 4; i++) {
                    float xv = s_x[(ty * 4 + i) * 132 + k];
                    acc[i][0] += xv * w.x; acc[i][1] += xv * w.y;
                    acc[i][2] += xv * w.z; acc[i][3] += xv * w.w;
                }
            }
            #pragma unroll
            for (int i = 0; i < 4; i++)
                #pragma unroll
                for (int j = 0; j < 4; j++) {
                    float v = acc[i][j];
                    s_h[(ty * 4 + i) * 64 + tx * 4 + j] = 0.5f * v * (1.0f + erff(v * 0.70710678118654752f));
                }
        }
        __syncthreads();
        // phase B: theta = pi*tanh(hmid @ w2 + b2) -> c,s   [64 x 32]
        float cr[2][4], sr[2][4];
        {
            const int tx = t & 7, ty = t >> 3;
            float4 bv = ((const float4*)b2)[tx];
            float acc[2][4];
            #pragma unroll
            for (int i = 0; i < 2; i++) { acc[i][0] = bv.x; acc[i][1] = bv.y; acc[i][2] = bv.z; acc[i][3] = bv.w; }
            for (int k = 0; k < 64; k++) {
                float4 w = ((float4*)s_w2)[k * 8 + tx];
                #pragma unroll
                for (int i = 0; i < 2; i++) {
                    float hv = s_h[(ty * 2 + i) * 64 + k];
                    acc[i][0] += hv * w.x; acc[i][1] += hv * w.y;
                    acc[i][2] += hv * w.z; acc[i][3] += hv * w.w;
                }
            }
            #pragma unroll
            for (int i = 0; i < 2; i++)
                #pragma unroll
                for (int j = 0; j < 4; j++) {
                    float th = 3.14159265358979323846f * tanhf(acc[i][j]);
                    sincosf(th, &sr[i][j], &cr[i][j]);
                }
        }
        __syncthreads();   // all hmid reads done; reuse s_h for c,s
        {
            const int tx = t & 7, ty = t >> 3;
            #pragma unroll
            for (int i = 0; i < 2; i++) {
                int r = ty * 2 + i;
                int n = base + r;
                float4 cv = make_float4(cr[i][0], cr[i][1], cr[i][2], cr[i][3]);
                float4 sv = make_float4(sr[i][0], sr[i][1], sr[i][2], sr[i][3]);
                ((float4*)&s_h[r * 64])[tx] = cv;
                ((float4*)&s_h[r * 64 + 32])[tx] = sv;
                if (n < n_nodes) {
                    ((float4*)&cs_out[(size_t)n * 64])[tx] = cv;
                    ((float4*)&cs_out[(size_t)n * 64 + 32])[tx] = sv;
                }
            }
        }
        __syncthreads();
        // phase C: rotate x tile in place (vf layout: [b][i][dd], d=2)
        for (int i = t; i < 64 * 32; i += 256) {
            int r = i >> 5, b = i & 31;
            float c = s_h[r * 64 + b], s = s_h[r * 64 + 32 + b];
            float* xr = &s_x[r * 132 + b * 4];
            float v00 = xr[0], v01 = xr[1], v10 = xr[2], v11 = xr[3];
            xr[0] = c * v00 - s * v10;
            xr[1] = c * v01 - s * v11;
            xr[2] = s * v00 + c * v10;
            xr[3] = s * v01 + c * v11;
        }
        __syncthreads();
        // phase D: h0 = bf16(rx @ lin_w + lin_b)     [64 x 128]
        {
            const int tx = t & 31, ty = t >> 5;
            float4 bv = ((const float4*)lin_b)[tx];
            float acc[8][4];
            #pragma unroll
            for (int i = 0; i < 8; i++) { acc[i][0] = bv.x; acc[i][1] = bv.y; acc[i][2] = bv.z; acc[i][3] = bv.w; }
            #pragma unroll 2
            for (int k = 0; k < 128; k++) {
                float4 w = ((const float4*)lin_w)[k * 32 + tx];
                #pragma unroll
                for (int i = 0; i < 8; i++) {
                    float xv = s_x[(ty * 8 + i) * 132 + k];
                    acc[i][0] += xv * w.x; acc[i][1] += xv * w.y;
                    acc[i][2] += xv * w.z; acc[i][3] += xv * w.w;
                }
            }
            #pragma unroll
            for (int i = 0; i < 8; i++) {
                int n = base + ty * 8 + i;
                if (n < n_nodes) {
                    uint2 pk;
                    pk.x = pack_bf16(acc[i][0], acc[i][1]);
                    pk.y = pack_bf16(acc[i][2], acc[i][3]);
                    ((uint2*)&h0[(size_t)n * 64])[tx] = pk;
                }
            }
        }
    }
}

// ---------------- propagation: one wave per node, bf16 state ----------------

__global__ __launch_bounds__(256) void prop_k(
    const uint* __restrict__ hin, uint* __restrict__ hout,
    const int* __restrict__ csr, const int* __restrict__ off,
    const int* __restrict__ cnt, const float* __restrict__ invdeg,
    const float* __restrict__ att_sm, int att_row, float* __restrict__ acc,
    int init_acc, int n_nodes)
{
    int gw = (int)((blockIdx.x * 256 + threadIdx.x) >> 6);
    int lane = threadIdx.x & 63;
    if (gw >= n_nodes) return;
    int o = off[gw], c = cnt[gw];
    size_t selfidx = (size_t)gw * 64 + lane;
    uint su = hin[selfidx];           // self loop (2 channels per lane)
    float ax = bf_lo(su), ay = bf_hi(su);
    int j = 0;
    for (; j + 8 <= c; j += 8) {
        int s0 = csr[o + j + 0], s1 = csr[o + j + 1], s2 = csr[o + j + 2], s3 = csr[o + j + 3];
        int s4 = csr[o + j + 4], s5 = csr[o + j + 5], s6 = csr[o + j + 6], s7 = csr[o + j + 7];
        uint v0 = hin[(size_t)s0 * 64 + lane];
        uint v1 = hin[(size_t)s1 * 64 + lane];
        uint v2 = hin[(size_t)s2 * 64 + lane];
        uint v3 = hin[(size_t)s3 * 64 + lane];
        uint v4 = hin[(size_t)s4 * 64 + lane];
        uint v5 = hin[(size_t)s5 * 64 + lane];
        uint v6 = hin[(size_t)s6 * 64 + lane];
        uint v7 = hin[(size_t)s7 * 64 + lane];
        ax += ((bf_lo(v0) + bf_lo(v1)) + (bf_lo(v2) + bf_lo(v3)))
            + ((bf_lo(v4) + bf_lo(v5)) + (bf_lo(v6) + bf_lo(v7)));
        ay += ((bf_hi(v0) + bf_hi(v1)) + (bf_hi(v2) + bf_hi(v3)))
            + ((bf_hi(v4) + bf_hi(v5)) + (bf_hi(v6) + bf_hi(v7)));
    }
    for (; j < c; ++j) {
        int s = csr[o + j];
        uint v = hin[(size_t)s * 64 + lane];
        ax += bf_lo(v); ay += bf_hi(v);
    }
    float id = invdeg[gw];
    ax *= id; ay *= id;
    hout[selfidx] = pack_bf16(ax, ay);
    if (att_row >= 0) {
        float wv = att_sm[att_row * 32 + (lane >> 1)];
        float2* a2 = (float2*)acc;
        float2 res = make_float2(wv * ax, wv * ay);
        if (!init_acc) { float2 p = a2[selfidx]; res.x += p.x; res.y += p.y; }
        a2[selfidx] = res;
    }
}

// ---------------- inverse rotation + residual ----------------

__global__ __launch_bounds__(256) void final_k(
    const float* __restrict__ x, const float* __restrict__ cs,
    float* __restrict__ out, int n_nodes)
{
    int i = blockIdx.x * 256 + threadIdx.x;   // (n, b)
    if (i >= n_nodes * 32) return;
    int n = i >> 5, b = i & 31;
    float c = cs[(size_t)n * 64 + b], s = cs[(size_t)n * 64 + 32 + b];
    float4 v = ((float4*)out)[i];             // acc lives in d_out
    float4 xv = ((const float4*)x)[i];
    float o0 =  c * v.x + s * v.z;
    float o1 =  c * v.y + s * v.w;
    float o2 = -s * v.x + c * v.z;
    float o3 = -s * v.y + c * v.w;
    ((float4*)out)[i] = make_float4(xv.x + o0, xv.y + o1, xv.z + o2, xv.w + o3);
}

// ---------------- launch ----------------

extern "C" void kernel_launch(void* const* d_in, const int* in_sizes, int n_in,
                              void* d_out, int out_size, void* d_ws, size_t ws_size,
                              hipStream_t stream) {
    const float* x     = (const float*)d_in[0];
    const int*   ei    = (const int*)d_in[1];
    const float* lin_w = (const float*)d_in[2];
    const float* lin_b = (const float*)d_in[3];
    const float* w1    = (const float*)d_in[4];
    const float* b1    = (const float*)d_in[5];
    const float* w2    = (const float*)d_in[6];
    const float* b2    = (const float*)d_in[7];
    const float* att   = (const float*)d_in[8];
    const int N = in_sizes[0] / 128;
    const int E = in_sizes[1] / 2;
    const int* srcp = ei;
    const int* dstp = ei + E;
    float* out = (float*)d_out;

    char* w = (char*)d_ws;
    auto walloc = [&](size_t bytes) { char* p = w; w += (bytes + 255) & ~255UL; return p; };
    int*   cnt    = (int*)walloc((size_t)N * 4);
    int*   deg    = (int*)walloc((size_t)N * 4);
    int*   off    = (int*)walloc((size_t)N * 4);
    int*   fil    = (int*)walloc((size_t)N * 4);
    float* invdeg = (float*)walloc((size_t)N * 4);
    int*   cursor = (int*)walloc(256);
    float* att_sm = (float*)walloc(512);
    int*   csr    = (int*)walloc((size_t)E * 4);
    float* cs     = (float*)walloc((size_t)N * 64 * 4);
    uint*  bufA   = (uint*)walloc((size_t)N * 64 * 4);   // bf16 h, 2 per uint
    uint*  bufB   = (uint*)walloc((size_t)N * 64 * 4);

    int nb_n = (N + 255) / 256;
    int nb_e = (E + 255) / 256;
    hipLaunchKernelGGL(init_k,  dim3(nb_n), dim3(256), 0, stream, cnt, deg, cursor, N);
    hipLaunchKernelGGL(count_k, dim3(nb_e), dim3(256), 0, stream, srcp, dstp, cnt, deg, E);
    hipLaunchKernelGGL(alloc_k, dim3(nb_n), dim3(256), 0, stream, cnt, deg, off, fil, invdeg, cursor, N);
    hipLaunchKernelGGL(fill_k,  dim3(nb_e), dim3(256), 0, stream, srcp, dstp, off, fil, csr, E);
    hipLaunchKernelGGL(att_k,   dim3(1),    dim3(64),  0, stream, att, att_sm);

    int n_tiles = (N + 63) / 64;
    hipLaunchKernelGGL(transform_k, dim3(1024), dim3(256), 0, stream,
                       x, lin_w, lin_b, w1, b1, w2, b2, bufA, cs, N, n_tiles);

    // 8 propagation steps; checkpoints (att rows) after steps 1,2,4,8
    int ckpt[9] = {-1, 0, 1, -1, 2, -1, -1, -1, 3};
    uint* hi = bufA; uint* ho = bufB;
    int pb = (N * 64 + 255) / 256;
    for (int step = 1; step <= 8; ++step) {
        hipLaunchKernelGGL(prop_k, dim3(pb), dim3(256), 0, stream,
                           hi, ho, csr, off, cnt, invdeg, att_sm, ckpt[step], out,
                           (step == 1) ? 1 : 0, N);
        uint* tmp = hi; hi = ho; ho = tmp;
    }

    int fb = (N * 32 + 255) / 256;
    hipLaunchKernelGGL(final_k, dim3(fb), dim3(256), 0, stream, x, cs, out, N);
}

// Round 3
// 1033.925 us; speedup vs baseline: 1.4093x; 1.0860x over previous
//
#include <hip/hip_runtime.h>
#include <math.h>

typedef unsigned int uint;

// ---------------- bf16 helpers ----------------

__device__ __forceinline__ float bf_lo(uint u) { return __uint_as_float(u << 16); }
__device__ __forceinline__ float bf_hi(uint u) { return __uint_as_float(u & 0xFFFF0000u); }
__device__ __forceinline__ uint pack_bf16(float x, float y) {
    uint ux = __float_as_uint(x), uy = __float_as_uint(y);
    ux += 0x7FFFu + ((ux >> 16) & 1u);          // RTNE
    uy += 0x7FFFu + ((uy >> 16) & 1u);
    return (ux >> 16) | (uy & 0xFFFF0000u);
}

// ---------------- CSR build ----------------

__global__ void init_k(int* cnt, int* deg, int* cursor, int n) {
    int i = blockIdx.x * 256 + threadIdx.x;
    if (i < n) { cnt[i] = 0; deg[i] = 1; }   // deg starts at 1 (self loop)
    if (i == 0) cursor[0] = 0;
}

__global__ void count_k(const int* __restrict__ src, const int* __restrict__ dst,
                        int* cnt, int* deg, int E) {
    int e = blockIdx.x * 256 + threadIdx.x;
    if (e < E) {
        atomicAdd(&cnt[dst[e]], 1);
        atomicAdd(&deg[src[e]], 1);
    }
}

__global__ void alloc_k(const int* __restrict__ cnt, const int* __restrict__ deg,
                        int* off, int* fil, float* invdeg, int* cursor, int n) {
    int i = blockIdx.x * 256 + threadIdx.x;
    if (i < n) {
        off[i] = atomicAdd(cursor, cnt[i]);
        fil[i] = 0;
        invdeg[i] = 1.0f / (float)deg[i];
    }
}

__global__ void fill_k(const int* __restrict__ src, const int* __restrict__ dst,
                       const int* __restrict__ off, int* fil, int* csr, int E) {
    int e = blockIdx.x * 256 + threadIdx.x;
    if (e < E) {
        int d = dst[e];
        int p = atomicAdd(&fil[d], 1);
        csr[off[d] + p] = src[e];
    }
}

// ---------------- attention softmax (tiny) ----------------

__global__ void att_k(const float* __restrict__ att, float* att_sm) {
    int b = threadIdx.x;
    if (b < 32) {
        float v0 = att[b], v1 = att[32 + b], v2 = att[64 + b], v3 = att[96 + b];
        float m = fmaxf(fmaxf(v0, v1), fmaxf(v2, v3));
        float e0 = expf(v0 - m), e1 = expf(v1 - m), e2 = expf(v2 - m), e3 = expf(v3 - m);
        float inv = 1.0f / (e0 + e1 + e2 + e3);
        att_sm[b] = e0 * inv; att_sm[32 + b] = e1 * inv;
        att_sm[64 + b] = e2 * inv; att_sm[96 + b] = e3 * inv;
    }
}

// ---------------- angles: cs = bf16(cos,sin of pi*tanh(gelu(x@w1+b1)@w2+b2)) ----
// LDS: w1 32KB + w2 8KB + x 16KB + h 8KB = 64.5KB -> 2 blocks/CU

__global__ __launch_bounds__(256) void angles_k(
    const float* __restrict__ x,
    const float* __restrict__ w1, const float* __restrict__ b1,
    const float* __restrict__ w2, const float* __restrict__ b2,
    uint* __restrict__ cs_out, int n_nodes, int n_tiles)
{
    __shared__ float s_w1[128 * 64];
    __shared__ float s_w2[64 * 32];
    __shared__ float s_x[32 * 128];
    __shared__ float s_h[32 * 64];
    const int t = threadIdx.x;

    for (int i = t; i < 128 * 64 / 4; i += 256) ((float4*)s_w1)[i] = ((const float4*)w1)[i];
    for (int i = t; i < 64 * 32 / 4; i += 256)  ((float4*)s_w2)[i] = ((const float4*)w2)[i];

    for (int tile = blockIdx.x; tile < n_tiles; tile += gridDim.x) {
        const int base = tile * 32;
        __syncthreads();
        // stage 32x128 x tile
        for (int i = t; i < 32 * 32; i += 256) {
            int r = i >> 5, q = i & 31;
            int n = base + r;
            float4 v = make_float4(0.f, 0.f, 0.f, 0.f);
            if (n < n_nodes) v = ((const float4*)x)[(size_t)n * 32 + q];
            ((float4*)&s_x[r * 128])[q] = v;
        }
        __syncthreads();
        // phase A: hmid = gelu(x @ w1 + b1)  [32 x 64]
        {
            const int tx = t & 15, ty = t >> 4;   // 16 col-f4 groups, 16 row groups (2 rows)
            float4 bv = ((const float4*)b1)[tx];
            float acc[2][4];
            #pragma unroll
            for (int i = 0; i < 2; i++) { acc[i][0] = bv.x; acc[i][1] = bv.y; acc[i][2] = bv.z; acc[i][3] = bv.w; }
            for (int k = 0; k < 128; k++) {
                float4 w = ((float4*)s_w1)[k * 16 + tx];
                #pragma unroll
                for (int i = 0; i < 2; i++) {
                    float xv = s_x[(ty * 2 + i) * 128 + k];
                    acc[i][0] += xv * w.x; acc[i][1] += xv * w.y;
                    acc[i][2] += xv * w.z; acc[i][3] += xv * w.w;
                }
            }
            #pragma unroll
            for (int i = 0; i < 2; i++)
                #pragma unroll
                for (int j = 0; j < 4; j++) {
                    float v = acc[i][j];
                    s_h[(ty * 2 + i) * 64 + tx * 4 + j] = 0.5f * v * (1.0f + erff(v * 0.70710678118654752f));
                }
        }
        __syncthreads();
        // phase B: theta = pi*tanh(hmid @ w2 + b2) -> packed bf16 (c,s)  [32 x 32]
        {
            const int tx = t & 7, ty = t >> 3;    // 8 col-f4 groups, 32 rows (1 row)
            float4 bv = ((const float4*)b2)[tx];
            float acc[4] = {bv.x, bv.y, bv.z, bv.w};
            for (int k = 0; k < 64; k++) {
                float4 w = ((float4*)s_w2)[k * 8 + tx];
                float hv = s_h[ty * 64 + k];
                acc[0] += hv * w.x; acc[1] += hv * w.y;
                acc[2] += hv * w.z; acc[3] += hv * w.w;
            }
            int n = base + ty;
            if (n < n_nodes) {
                uint4 pk;
                float c, s, th;
                th = 3.14159265358979323846f * tanhf(acc[0]); sincosf(th, &s, &c); pk.x = pack_bf16(c, s);
                th = 3.14159265358979323846f * tanhf(acc[1]); sincosf(th, &s, &c); pk.y = pack_bf16(c, s);
                th = 3.14159265358979323846f * tanhf(acc[2]); sincosf(th, &s, &c); pk.z = pack_bf16(c, s);
                th = 3.14159265358979323846f * tanhf(acc[3]); sincosf(th, &s, &c); pk.w = pack_bf16(c, s);
                ((uint4*)&cs_out[(size_t)n * 32])[tx] = pk;
            }
        }
    }
}

// ---------------- rotate + linear: h0 = bf16((R x) @ lin_w + lin_b) ----------
// LDS: lin_w 64KB + x 16KB = 80KB -> 2 blocks/CU

__global__ __launch_bounds__(256) void rotlin_k(
    const float* __restrict__ x, const uint* __restrict__ cs,
    const float* __restrict__ lin_w, const float* __restrict__ lin_b,
    uint* __restrict__ h0, int n_nodes, int n_tiles)
{
    __shared__ float s_lw[128 * 128];
    __shared__ float s_x[32 * 128];
    const int t = threadIdx.x;

    for (int i = t; i < 128 * 128 / 4; i += 256) ((float4*)s_lw)[i] = ((const float4*)lin_w)[i];

    for (int tile = blockIdx.x; tile < n_tiles; tile += gridDim.x) {
        const int base = tile * 32;
        __syncthreads();
        // stage 32x128 x tile
        for (int i = t; i < 32 * 32; i += 256) {
            int r = i >> 5, q = i & 31;
            int n = base + r;
            float4 v = make_float4(0.f, 0.f, 0.f, 0.f);
            if (n < n_nodes) v = ((const float4*)x)[(size_t)n * 32 + q];
            ((float4*)&s_x[r * 128])[q] = v;
        }
        __syncthreads();
        // rotate in place
        for (int i = t; i < 32 * 32; i += 256) {
            int r = i >> 5, b = i & 31;
            int n = base + r;
            if (n < n_nodes) {
                uint csu = cs[(size_t)n * 32 + b];
                float c = bf_lo(csu), s = bf_hi(csu);
                float* xr = &s_x[r * 128 + b * 4];
                float v00 = xr[0], v01 = xr[1], v10 = xr[2], v11 = xr[3];
                xr[0] = c * v00 - s * v10;
                xr[1] = c * v01 - s * v11;
                xr[2] = s * v00 + c * v10;
                xr[3] = s * v01 + c * v11;
            }
        }
        __syncthreads();
        // GEMM: 32x128 @ 128x128 + b  -> bf16
        {
            const int tx = t & 31, ty = t >> 5;   // 32 col-f4 groups, 8 row groups (4 rows)
            float4 bv = ((const float4*)lin_b)[tx];
            float acc[4][4];
            #pragma unroll
            for (int i = 0; i < 4; i++) { acc[i][0] = bv.x; acc[i][1] = bv.y; acc[i][2] = bv.z; acc[i][3] = bv.w; }
            for (int k = 0; k < 128; k++) {
                float4 w = ((float4*)s_lw)[k * 32 + tx];
                #pragma unroll
                for (int i = 0; i < 4; i++) {
                    float xv = s_x[(ty * 4 + i) * 128 + k];
                    acc[i][0] += xv * w.x; acc[i][1] += xv * w.y;
                    acc[i][2] += xv * w.z; acc[i][3] += xv * w.w;
                }
            }
            #pragma unroll
            for (int i = 0; i < 4; i++) {
                int n = base + ty * 4 + i;
                if (n < n_nodes) {
                    uint2 pk;
                    pk.x = pack_bf16(acc[i][0], acc[i][1]);
                    pk.y = pack_bf16(acc[i][2], acc[i][3]);
                    ((uint2*)&h0[(size_t)n * 64])[tx] = pk;
                }
            }
        }
    }
}

// ---------------- propagation: one wave per node, bf16 state ----------------

__global__ __launch_bounds__(256) void prop_k(
    const uint* __restrict__ hin, uint* __restrict__ hout,
    const int* __restrict__ csr, const int* __restrict__ off,
    const int* __restrict__ cnt, const float* __restrict__ invdeg,
    const float* __restrict__ att_sm, int att_row, float* __restrict__ acc,
    int init_acc, int n_nodes)
{
    int gw = (int)((blockIdx.x * 256 + threadIdx.x) >> 6);
    int lane = threadIdx.x & 63;
    if (gw >= n_nodes) return;
    int o = off[gw], c = cnt[gw];
    size_t selfidx = (size_t)gw * 64 + lane;
    uint su = hin[selfidx];           // self loop (2 channels per lane)
    float ax = bf_lo(su), ay = bf_hi(su);
    int j = 0;
    for (; j + 8 <= c; j += 8) {
        int s0 = csr[o + j + 0], s1 = csr[o + j + 1], s2 = csr[o + j + 2], s3 = csr[o + j + 3];
        int s4 = csr[o + j + 4], s5 = csr[o + j + 5], s6 = csr[o + j + 6], s7 = csr[o + j + 7];
        uint v0 = hin[(size_t)s0 * 64 + lane];
        uint v1 = hin[(size_t)s1 * 64 + lane];
        uint v2 = hin[(size_t)s2 * 64 + lane];
        uint v3 = hin[(size_t)s3 * 64 + lane];
        uint v4 = hin[(size_t)s4 * 64 + lane];
        uint v5 = hin[(size_t)s5 * 64 + lane];
        uint v6 = hin[(size_t)s6 * 64 + lane];
        uint v7 = hin[(size_t)s7 * 64 + lane];
        ax += ((bf_lo(v0) + bf_lo(v1)) + (bf_lo(v2) + bf_lo(v3)))
            + ((bf_lo(v4) + bf_lo(v5)) + (bf_lo(v6) + bf_lo(v7)));
        ay += ((bf_hi(v0) + bf_hi(v1)) + (bf_hi(v2) + bf_hi(v3)))
            + ((bf_hi(v4) + bf_hi(v5)) + (bf_hi(v6) + bf_hi(v7)));
    }
    for (; j < c; ++j) {
        int s = csr[o + j];
        uint v = hin[(size_t)s * 64 + lane];
        ax += bf_lo(v); ay += bf_hi(v);
    }
    float id = invdeg[gw];
    ax *= id; ay *= id;
    hout[selfidx] = pack_bf16(ax, ay);
    if (att_row >= 0) {
        float wv = att_sm[att_row * 32 + (lane >> 1)];
        float2* a2 = (float2*)acc;
        float2 res = make_float2(wv * ax, wv * ay);
        if (!init_acc) { float2 p = a2[selfidx]; res.x += p.x; res.y += p.y; }
        a2[selfidx] = res;
    }
}

// ---------------- final: attention combine + inverse rotation + residual -----

__global__ __launch_bounds__(256) void final2_k(
    const float* __restrict__ x, const uint* __restrict__ cs,
    const uint* __restrict__ c1, const uint* __restrict__ c2,
    const uint* __restrict__ c4, const uint* __restrict__ c8,
    const float* __restrict__ att_sm, float* __restrict__ out, int n_nodes)
{
    __shared__ float s_att[128];
    int t = threadIdx.x;
    if (t < 128) s_att[t] = att_sm[t];
    __syncthreads();
    int i = blockIdx.x * 256 + t;     // (n, b)
    if (i >= n_nodes * 32) return;
    int b = i & 31;
    uint2 u1 = ((const uint2*)c1)[i];
    uint2 u2 = ((const uint2*)c2)[i];
    uint2 u4 = ((const uint2*)c4)[i];
    uint2 u8 = ((const uint2*)c8)[i];
    float w0 = s_att[b], w1 = s_att[32 + b], w2 = s_att[64 + b], w3 = s_att[96 + b];
    float h0 = w0 * bf_lo(u1.x) + w1 * bf_lo(u2.x) + w2 * bf_lo(u4.x) + w3 * bf_lo(u8.x);
    float h1 = w0 * bf_hi(u1.x) + w1 * bf_hi(u2.x) + w2 * bf_hi(u4.x) + w3 * bf_hi(u8.x);
    float h2 = w0 * bf_lo(u1.y) + w1 * bf_lo(u2.y) + w2 * bf_lo(u4.y) + w3 * bf_lo(u8.y);
    float h3 = w0 * bf_hi(u1.y) + w1 * bf_hi(u2.y) + w2 * bf_hi(u4.y) + w3 * bf_hi(u8.y);
    uint csu = cs[i];
    float c = bf_lo(csu), s = bf_hi(csu);
    float4 xv = ((const float4*)x)[i];
    ((float4*)out)[i] = make_float4(
        xv.x + ( c * h0 + s * h2),
        xv.y + ( c * h1 + s * h3),
        xv.z + (-s * h0 + c * h2),
        xv.w + (-s * h1 + c * h3));
}

// fallback final (acc lives fp32 in d_out)
__global__ __launch_bounds__(256) void final_k(
    const float* __restrict__ x, const uint* __restrict__ cs,
    float* __restrict__ out, int n_nodes)
{
    int i = blockIdx.x * 256 + threadIdx.x;   // (n, b)
    if (i >= n_nodes * 32) return;
    uint csu = cs[i];
    float c = bf_lo(csu), s = bf_hi(csu);
    float4 v = ((float4*)out)[i];
    float4 xv = ((const float4*)x)[i];
    ((float4*)out)[i] = make_float4(
        xv.x + ( c * v.x + s * v.z),
        xv.y + ( c * v.y + s * v.w),
        xv.z + (-s * v.x + c * v.z),
        xv.w + (-s * v.y + c * v.w));
}

// ---------------- launch ----------------

extern "C" void kernel_launch(void* const* d_in, const int* in_sizes, int n_in,
                              void* d_out, int out_size, void* d_ws, size_t ws_size,
                              hipStream_t stream) {
    const float* x     = (const float*)d_in[0];
    const int*   ei    = (const int*)d_in[1];
    const float* lin_w = (const float*)d_in[2];
    const float* lin_b = (const float*)d_in[3];
    const float* w1    = (const float*)d_in[4];
    const float* b1    = (const float*)d_in[5];
    const float* w2    = (const float*)d_in[6];
    const float* b2    = (const float*)d_in[7];
    const float* att   = (const float*)d_in[8];
    const int N = in_sizes[0] / 128;
    const int E = in_sizes[1] / 2;
    const int* srcp = ei;
    const int* dstp = ei + E;
    float* out = (float*)d_out;

    char* w = (char*)d_ws;
    size_t used = 0;
    auto walloc = [&](size_t bytes) {
        char* p = w; size_t a = (bytes + 255) & ~255UL; w += a; used += a; return p;
    };
    int*   cnt    = (int*)walloc((size_t)N * 4);
    int*   deg    = (int*)walloc((size_t)N * 4);
    int*   off    = (int*)walloc((size_t)N * 4);
    int*   fil    = (int*)walloc((size_t)N * 4);
    float* invdeg = (float*)walloc((size_t)N * 4);
    int*   cursor = (int*)walloc(256);
    float* att_sm = (float*)walloc(512);
    int*   csr    = (int*)walloc((size_t)E * 4);
    uint*  cs     = (uint*)walloc((size_t)N * 32 * 4);     // bf16 (c,s) packed

    size_t bufBytes = (size_t)N * 64 * 4;                  // one bf16 h buffer
    size_t remain = (ws_size > used) ? (ws_size - used) : 0;
    bool big = remain >= 5 * (bufBytes + 256);

    int nb_n = (N + 255) / 256;
    int nb_e = (E + 255) / 256;
    hipLaunchKernelGGL(init_k,  dim3(nb_n), dim3(256), 0, stream, cnt, deg, cursor, N);
    hipLaunchKernelGGL(count_k, dim3(nb_e), dim3(256), 0, stream, srcp, dstp, cnt, deg, E);
    hipLaunchKernelGGL(alloc_k, dim3(nb_n), dim3(256), 0, stream, cnt, deg, off, fil, invdeg, cursor, N);
    hipLaunchKernelGGL(fill_k,  dim3(nb_e), dim3(256), 0, stream, srcp, dstp, off, fil, csr, E);
    hipLaunchKernelGGL(att_k,   dim3(1),    dim3(64),  0, stream, att, att_sm);

    int n_tiles = (N + 31) / 32;
    int pb = (N * 64 + 255) / 256;
    int fb = (N * 32 + 255) / 256;

    if (big) {
        uint* T0 = (uint*)walloc(bufBytes);
        uint* C1 = (uint*)walloc(bufBytes);
        uint* C2 = (uint*)walloc(bufBytes);
        uint* C4 = (uint*)walloc(bufBytes);
        uint* C8 = (uint*)walloc(bufBytes);

        hipLaunchKernelGGL(angles_k, dim3(512), dim3(256), 0, stream,
                           x, w1, b1, w2, b2, cs, N, n_tiles);
        hipLaunchKernelGGL(rotlin_k, dim3(512), dim3(256), 0, stream,
                           x, cs, lin_w, lin_b, T0, N, n_tiles);

        // 8 steps over 5 buffers; checkpoints preserved: h1=C1, h2=C2, h4=C4, h8=C8
        uint* seq_in [8] = {T0, C1, C2, T0, C4, T0, C8, T0};
        uint* seq_out[8] = {C1, C2, T0, C4, T0, C8, T0, C8};
        for (int step = 0; step < 8; ++step) {
            hipLaunchKernelGGL(prop_k, dim3(pb), dim3(256), 0, stream,
                               seq_in[step], seq_out[step], csr, off, cnt, invdeg,
                               att_sm, -1, out, 0, N);
        }
        hipLaunchKernelGGL(final2_k, dim3(fb), dim3(256), 0, stream,
                           x, cs, C1, C2, C4, C8, att_sm, out, N);
    } else {
        uint* bufA = (uint*)walloc(bufBytes);
        uint* bufB = (uint*)walloc(bufBytes);

        hipLaunchKernelGGL(angles_k, dim3(512), dim3(256), 0, stream,
                           x, w1, b1, w2, b2, cs, N, n_tiles);
        hipLaunchKernelGGL(rotlin_k, dim3(512), dim3(256), 0, stream,
                           x, cs, lin_w, lin_b, bufA, N, n_tiles);

        int ckpt[9] = {-1, 0, 1, -1, 2, -1, -1, -1, 3};
        uint* hi = bufA; uint* ho = bufB;
        for (int step = 1; step <= 8; ++step) {
            hipLaunchKernelGGL(prop_k, dim3(pb), dim3(256), 0, stream,
                               hi, ho, csr, off, cnt, invdeg, att_sm, ckpt[step], out,
                               (step == 1) ? 1 : 0, N);
            uint* tmp = hi; hi = ho; ho = tmp;
        }
        hipLaunchKernelGGL(final_k, dim3(fb), dim3(256), 0, stream, x, cs, out, N);
    }
}